// Round 1
// baseline (487.466 us; speedup 1.0000x reference)
//
#include <hip/hip_runtime.h>

// HyperLSTMCell on MI355X (gfx950).
// B=65536, D=128, H=256, Z=128, E=16. All inputs/outputs f32; internal GEMMs bf16 MFMA.
//
// Pipeline (all on `stream`, stream-ordered deps):
//   prep : permute/cast weights to bf16 LDS-image tiles (gate-gathered virtual col
//          order v = hb*256 + gate*64 + hh; pre-swizzled with the LDS XOR swizzle)
//   k1   : gh = [hhat0|h0|x] @ hweight + hbias ; hyper LSTM -> hhat1, chat1 (to d_out)
//   k15  : z = hhat1 @ [zw_h|zw_x|zw_b] + [zb_h|zb_x|0]  -> zbuf bf16 [B,192]
//   k2   : gpre = [h0|x]@weight (K=384); d_y* = z_slice @ dw_blockdiag (K=64 x3);
//          g = gpre*d_yh*d_yx + d_yb + bias ; LSTM -> h1, c1 (to d_out)
//
// d_out layout (f32): h1 [B,256] | c1 [B,256] | hhat1 [B,128] | chat1 [B,128]

typedef unsigned short u16;
typedef __attribute__((ext_vector_type(8))) short bf16x8;   // 8 bf16 (4 VGPRs)
typedef __attribute__((ext_vector_type(4))) float f32x4;

#define BATCH 65536

__device__ __forceinline__ u16 f2b(float f) {           // f32 -> bf16 bits, RNE
  unsigned u = __float_as_uint(f);
  u += 0x7fffu + ((u >> 16) & 1u);
  return (u16)(u >> 16);
}
__device__ __forceinline__ float sigf(float x) { return 1.0f / (1.0f + __expf(-x)); }
// LDS XOR swizzle for [row][64] bf16 tiles (G4: breaks the 128B-row-stride conflict).
__device__ __forceinline__ int swz(int r, int c) { return r * 64 + (c ^ ((r & 7) << 3)); }

// ---------------------------------------------------------------------------
// prep: weight permute + bf16 cast + pre-swizzle into 256x64 LDS-image tiles
// ---------------------------------------------------------------------------
__global__ void hlstm_prep(
    const float* __restrict__ hweight, const float* __restrict__ hbias,
    const float* __restrict__ zw_h, const float* __restrict__ zw_x, const float* __restrict__ zw_b,
    const float* __restrict__ zb_h, const float* __restrict__ zb_x,
    const float* __restrict__ dw_h, const float* __restrict__ dw_x, const float* __restrict__ dw_b,
    const float* __restrict__ weight, const float* __restrict__ bias,
    u16* __restrict__ hw_ts, float* __restrict__ hbias_r,
    u16* __restrict__ w_ts,  float* __restrict__ bias_r,
    u16* __restrict__ dwh_ts, u16* __restrict__ dwx_ts, u16* __restrict__ dwb_ts,
    u16* __restrict__ zw_ts, float* __restrict__ zbias_r)
{
  const int tid = blockIdx.x * blockDim.x + threadIdx.x;
  const int nt  = gridDim.x * blockDim.x;

  // hw_ts: [hb(2)][ks(8)] tiles of [n=256][kk=64], element stored at swz(n,kk)
  for (int i = tid; i < 2 * 8 * 16384; i += nt) {
    int tile = i >> 14, idx = i & 16383;
    int hb = tile >> 3, ks = tile & 7;
    int n = idx >> 6, kk = (idx & 63) ^ ((n & 7) << 3);
    int gate = (n >> 6) & 3, hh = n & 63;
    int k = ks * 64 + kk;
    int col = gate * 128 + hb * 64 + hh;          // phys col in hweight [512,512]
    hw_ts[i] = f2b(hweight[k * 512 + col]);
  }
  // w_ts: [hb(4)][ks(6)] tiles
  for (int i = tid; i < 4 * 6 * 16384; i += nt) {
    int tile = i >> 14, idx = i & 16383;
    int hb = tile / 6, ks = tile % 6;
    int n = idx >> 6, kk = (idx & 63) ^ ((n & 7) << 3);
    int gate = (n >> 6) & 3, hh = n & 63;
    int k = ks * 64 + kk;
    int col = gate * 256 + hb * 64 + hh;          // phys col in weight [384,1024]
    w_ts[i] = f2b(weight[k * 1024 + col]);
  }
  // dw*_ts: [hb(4)] tiles of block-diagonal (gate) dw, rows kk = gate*16+e
  for (int i = tid; i < 4 * 16384; i += nt) {
    int hb = i >> 14, idx = i & 16383;
    int n = idx >> 6, kk = (idx & 63) ^ ((n & 7) << 3);
    int gate = (n >> 6) & 3, hh = n & 63;
    int h = hb * 64 + hh;
    u16 vh = 0, vx = 0, vb = 0;
    if ((kk >> 4) == gate) {
      int e = kk & 15;
      vh = f2b(dw_h[gate * 4096 + e * 256 + h]);
      vx = f2b(dw_x[gate * 4096 + e * 256 + h]);
      vb = f2b(dw_b[gate * 4096 + e * 256 + h]);
    }
    dwh_ts[i] = vh; dwx_ts[i] = vx; dwb_ts[i] = vb;
  }
  // zw_ts: [ks(2)] tiles of [n=192][kk=64]; n: 0:64 zw_h | 64:128 zw_x | 128:192 zw_b
  for (int i = tid; i < 2 * 12288; i += nt) {
    int ks = i / 12288, idx = i % 12288;
    int n = idx >> 6, kk = (idx & 63) ^ ((n & 7) << 3);
    int k = ks * 64 + kk;
    float v;
    if (n < 64)       v = zw_h[k * 64 + n];
    else if (n < 128) v = zw_x[k * 64 + n - 64];
    else              v = zw_b[k * 64 + n - 128];
    zw_ts[i] = f2b(v);
  }
  for (int i = tid; i < 512; i += nt) {
    int gate = (i >> 6) & 3, hb = i >> 8, hh = i & 63;
    hbias_r[i] = hbias[gate * 128 + hb * 64 + hh];
  }
  for (int i = tid; i < 1024; i += nt) {
    int gate = (i >> 6) & 3, hb = i >> 8, hh = i & 63;
    bias_r[i] = bias[gate * 256 + hb * 64 + hh];
  }
  for (int i = tid; i < 192; i += nt) {
    zbias_r[i] = (i < 64) ? zb_h[i] : (i < 128 ? zb_x[i - 64] : 0.0f);
  }
}

// ---------------------------------------------------------------------------
// k1: hyper GEMM + hyper LSTM cell.  grid (1024, 2), 256 threads (4 waves).
// Block: 64 rows x 256 virtual cols (4 gates x 64 z-cols), K = 512 in 8 steps.
// ---------------------------------------------------------------------------
__global__ __launch_bounds__(256) void hlstm_k1(
    const float* __restrict__ x, const float* __restrict__ h0,
    const float* __restrict__ hhat0, const float* __restrict__ chat0,
    const u16* __restrict__ hw_ts, const float* __restrict__ hbias_r,
    float* __restrict__ d_out)
{
  __shared__ alignas(16) u16 lA[64 * 64];
  __shared__ alignas(16) u16 lB[256 * 64];
  const int rb = blockIdx.x, hb = blockIdx.y;
  const int t = threadIdx.x;
  const int lane = t & 63, wc = t >> 6;       // wave -> 16-col slice
  const int lr = lane & 15, kg = lane >> 4;
  const int ar = t >> 2, aq = t & 3;          // A staging: row, quarter

  f32x4 acc[4][4];
  const f32x4 zzero = {0.f, 0.f, 0.f, 0.f};
#pragma unroll
  for (int mf = 0; mf < 4; ++mf)
#pragma unroll
    for (int g = 0; g < 4; ++g) acc[mf][g] = zzero;

#pragma unroll
  for (int ks = 0; ks < 8; ++ks) {
    const int kbase = ks * 64;
    __syncthreads();
    { // stage A: f32 -> bf16 cast, swizzled LDS write
      const float* src; int ld, coff;
      if (kbase < 128)      { src = hhat0; ld = 128; coff = kbase; }
      else if (kbase < 384) { src = h0;    ld = 256; coff = kbase - 128; }
      else                  { src = x;     ld = 128; coff = kbase - 384; }
      const float* p = src + (size_t)(rb * 64 + ar) * ld + coff + aq * 16;
      alignas(16) u16 tmp[16];
#pragma unroll
      for (int i = 0; i < 4; ++i) {
        float4 v = ((const float4*)p)[i];
        tmp[i*4+0] = f2b(v.x); tmp[i*4+1] = f2b(v.y);
        tmp[i*4+2] = f2b(v.z); tmp[i*4+3] = f2b(v.w);
      }
      *(uint4*)&lA[swz(ar, aq * 16)]     = *(const uint4*)&tmp[0];
      *(uint4*)&lA[swz(ar, aq * 16 + 8)] = *(const uint4*)&tmp[8];
    }
    { // stage B: pre-swizzled tile, coalesced copy, linear LDS write
      const u16* p = hw_ts + (size_t)(hb * 8 + ks) * 16384;
#pragma unroll
      for (int i = 0; i < 8; ++i) {
        uint4 v = *(const uint4*)(p + (i * 256 + t) * 8);
        *(uint4*)&lB[(i * 256 + t) * 8] = v;
      }
    }
    __syncthreads();
#pragma unroll
    for (int h = 0; h < 2; ++h) {
      bf16x8 bfr[4];
#pragma unroll
      for (int g = 0; g < 4; ++g)
        bfr[g] = *(const bf16x8*)&lB[swz(g * 64 + wc * 16 + lr, h * 32 + kg * 8)];
#pragma unroll
      for (int mf = 0; mf < 4; ++mf) {
        bf16x8 afr = *(const bf16x8*)&lA[swz(mf * 16 + lr, h * 32 + kg * 8)];
#pragma unroll
        for (int g = 0; g < 4; ++g)
          acc[mf][g] = __builtin_amdgcn_mfma_f32_16x16x32_bf16(afr, bfr[g], acc[mf][g], 0, 0, 0);
      }
    }
  }

  // epilogue: hyper LSTM (all 4 gates in-lane thanks to gate-gathered layout)
  float hb4[4];
#pragma unroll
  for (int g = 0; g < 4; ++g) hb4[g] = hbias_r[hb * 256 + g * 64 + wc * 16 + lr];
  const int zc = hb * 64 + wc * 16 + lr;
  float* out_hh = d_out + (size_t)BATCH * 512;
  float* out_ch = d_out + (size_t)BATCH * 640;
#pragma unroll
  for (int mf = 0; mf < 4; ++mf)
#pragma unroll
    for (int r = 0; r < 4; ++r) {
      const int row = rb * 64 + mf * 16 + kg * 4 + r;
      const float gi = acc[mf][0][r] + hb4[0];
      const float gg = acc[mf][1][r] + hb4[1];
      const float gf = acc[mf][2][r] + hb4[2];
      const float go = acc[mf][3][r] + hb4[3];
      const float c0v = chat0[(size_t)row * 128 + zc];
      const float c1v = sigf(gf) * c0v + sigf(gi) * tanhf(gg);
      const float h1v = sigf(go) * tanhf(c1v);
      out_hh[(size_t)row * 128 + zc] = h1v;
      out_ch[(size_t)row * 128 + zc] = c1v;
    }
}

// ---------------------------------------------------------------------------
// k15: z = hhat1 @ zw_cat + zb_cat -> zbuf bf16 [B,192]. grid 1024, 256 thr.
// ---------------------------------------------------------------------------
__global__ __launch_bounds__(256) void hlstm_k15(
    const float* __restrict__ hhat1, const u16* __restrict__ zw_ts,
    const float* __restrict__ zbias_r, u16* __restrict__ zbuf)
{
  __shared__ alignas(16) u16 lA[64 * 64];
  __shared__ alignas(16) u16 lB[192 * 64];
  const int rb = blockIdx.x;
  const int t = threadIdx.x;
  const int lane = t & 63, wc = t >> 6;
  const int lr = lane & 15, kg = lane >> 4;
  const int ar = t >> 2, aq = t & 3;

  f32x4 acc[4][3];
  const f32x4 zzero = {0.f, 0.f, 0.f, 0.f};
#pragma unroll
  for (int mf = 0; mf < 4; ++mf)
#pragma unroll
    for (int g = 0; g < 3; ++g) acc[mf][g] = zzero;

#pragma unroll
  for (int ks = 0; ks < 2; ++ks) {
    const int kbase = ks * 64;
    __syncthreads();
    {
      const float* p = hhat1 + (size_t)(rb * 64 + ar) * 128 + kbase + aq * 16;
      alignas(16) u16 tmp[16];
#pragma unroll
      for (int i = 0; i < 4; ++i) {
        float4 v = ((const float4*)p)[i];
        tmp[i*4+0] = f2b(v.x); tmp[i*4+1] = f2b(v.y);
        tmp[i*4+2] = f2b(v.z); tmp[i*4+3] = f2b(v.w);
      }
      *(uint4*)&lA[swz(ar, aq * 16)]     = *(const uint4*)&tmp[0];
      *(uint4*)&lA[swz(ar, aq * 16 + 8)] = *(const uint4*)&tmp[8];
    }
    { // 12288 elems = 1536 16B-chunks, 256 threads x 6
      const u16* p = zw_ts + (size_t)ks * 12288;
#pragma unroll
      for (int i = 0; i < 6; ++i) {
        uint4 v = *(const uint4*)(p + (i * 256 + t) * 8);
        *(uint4*)&lB[(i * 256 + t) * 8] = v;
      }
    }
    __syncthreads();
#pragma unroll
    for (int h = 0; h < 2; ++h) {
      bf16x8 bfr[3];
#pragma unroll
      for (int g = 0; g < 3; ++g)
        bfr[g] = *(const bf16x8*)&lB[swz(wc * 48 + g * 16 + lr, h * 32 + kg * 8)];
#pragma unroll
      for (int mf = 0; mf < 4; ++mf) {
        bf16x8 afr = *(const bf16x8*)&lA[swz(mf * 16 + lr, h * 32 + kg * 8)];
#pragma unroll
        for (int g = 0; g < 3; ++g)
          acc[mf][g] = __builtin_amdgcn_mfma_f32_16x16x32_bf16(afr, bfr[g], acc[mf][g], 0, 0, 0);
      }
    }
  }
#pragma unroll
  for (int g = 0; g < 3; ++g) {
    const int col = wc * 48 + g * 16 + lr;
    const float zb = zbias_r[col];
#pragma unroll
    for (int mf = 0; mf < 4; ++mf)
#pragma unroll
      for (int r = 0; r < 4; ++r) {
        const int row = rb * 64 + mf * 16 + kg * 4 + r;
        zbuf[(size_t)row * 192 + col] = f2b(acc[mf][g][r] + zb);
      }
  }
}

// ---------------------------------------------------------------------------
// k2: main GEMM (K=384) + 3 block-diagonal d-GEMMs (K=64) + LSTM epilogue.
// grid (1024, 4), 256 threads. 4 sequential K-phases share one spare acc set.
// ---------------------------------------------------------------------------
__global__ __launch_bounds__(256) void hlstm_k2(
    const float* __restrict__ x, const float* __restrict__ h0,
    const float* __restrict__ c0,
    const u16* __restrict__ w_ts, const float* __restrict__ bias_r,
    const u16* __restrict__ dwh_ts, const u16* __restrict__ dwx_ts, const u16* __restrict__ dwb_ts,
    const u16* __restrict__ zbuf, float* __restrict__ d_out)
{
  __shared__ alignas(16) u16 lA[64 * 64];
  __shared__ alignas(16) u16 lB[256 * 64];
  const int rb = blockIdx.x, hb = blockIdx.y;
  const int t = threadIdx.x;
  const int lane = t & 63, wc = t >> 6;
  const int lr = lane & 15, kg = lane >> 4;
  const int ar = t >> 2, aq = t & 3;

  f32x4 acc1[4][4], acc2[4][4];
  const f32x4 zzero = {0.f, 0.f, 0.f, 0.f};
#pragma unroll
  for (int mf = 0; mf < 4; ++mf)
#pragma unroll
    for (int g = 0; g < 4; ++g) acc1[mf][g] = zzero;

  auto stageB = [&](const u16* tile) {
#pragma unroll
    for (int i = 0; i < 8; ++i) {
      uint4 v = *(const uint4*)(tile + (i * 256 + t) * 8);
      *(uint4*)&lB[(i * 256 + t) * 8] = v;
    }
  };
  auto sweep = [&](f32x4 (&acc)[4][4]) {
#pragma unroll
    for (int h = 0; h < 2; ++h) {
      bf16x8 bfr[4];
#pragma unroll
      for (int g = 0; g < 4; ++g)
        bfr[g] = *(const bf16x8*)&lB[swz(g * 64 + wc * 16 + lr, h * 32 + kg * 8)];
#pragma unroll
      for (int mf = 0; mf < 4; ++mf) {
        bf16x8 afr = *(const bf16x8*)&lA[swz(mf * 16 + lr, h * 32 + kg * 8)];
#pragma unroll
        for (int g = 0; g < 4; ++g)
          acc[mf][g] = __builtin_amdgcn_mfma_f32_16x16x32_bf16(afr, bfr[g], acc[mf][g], 0, 0, 0);
      }
    }
  };

  // ---- Phase 1: gpre = [h0|x] @ weight (K = 384)
#pragma unroll
  for (int ks = 0; ks < 6; ++ks) {
    const int kbase = ks * 64;
    __syncthreads();
    {
      const float* src; int ld, coff;
      if (kbase < 256) { src = h0; ld = 256; coff = kbase; }
      else             { src = x;  ld = 128; coff = kbase - 256; }
      const float* p = src + (size_t)(rb * 64 + ar) * ld + coff + aq * 16;
      alignas(16) u16 tmp[16];
#pragma unroll
      for (int i = 0; i < 4; ++i) {
        float4 v = ((const float4*)p)[i];
        tmp[i*4+0] = f2b(v.x); tmp[i*4+1] = f2b(v.y);
        tmp[i*4+2] = f2b(v.z); tmp[i*4+3] = f2b(v.w);
      }
      *(uint4*)&lA[swz(ar, aq * 16)]     = *(const uint4*)&tmp[0];
      *(uint4*)&lA[swz(ar, aq * 16 + 8)] = *(const uint4*)&tmp[8];
    }
    stageB(w_ts + (size_t)(hb * 6 + ks) * 16384);
    __syncthreads();
    sweep(acc1);
  }

  // ---- Phases 2..4: d_yh, d_yx, d_yb (A = z slices from zbuf, already bf16)
#pragma unroll
  for (int ph = 0; ph < 3; ++ph) {
    const u16* dwt = (ph == 0) ? dwh_ts : (ph == 1) ? dwx_ts : dwb_ts;
#pragma unroll
    for (int mf = 0; mf < 4; ++mf)
#pragma unroll
      for (int g = 0; g < 4; ++g) acc2[mf][g] = zzero;
    __syncthreads();
    {
      const u16* p = zbuf + (size_t)(rb * 64 + ar) * 192 + ph * 64 + aq * 16;
      uint4 v0 = ((const uint4*)p)[0];
      uint4 v1 = ((const uint4*)p)[1];
      *(uint4*)&lA[swz(ar, aq * 16)]     = v0;
      *(uint4*)&lA[swz(ar, aq * 16 + 8)] = v1;
    }
    stageB(dwt + (size_t)hb * 16384);
    __syncthreads();
    sweep(acc2);
    // g = gpre * d_yh * d_yx + d_yb   (bias added in epilogue)
#pragma unroll
    for (int mf = 0; mf < 4; ++mf)
#pragma unroll
      for (int g = 0; g < 4; ++g)
#pragma unroll
        for (int r = 0; r < 4; ++r) {
          if (ph < 2) acc1[mf][g][r] *= acc2[mf][g][r];
          else        acc1[mf][g][r] += acc2[mf][g][r];
        }
  }

  // ---- Epilogue: main LSTM cell
  float b4[4];
#pragma unroll
  for (int g = 0; g < 4; ++g) b4[g] = bias_r[hb * 256 + g * 64 + wc * 16 + lr];
  const int hcol = hb * 64 + wc * 16 + lr;
  float* out_c1 = d_out + (size_t)BATCH * 256;
#pragma unroll
  for (int mf = 0; mf < 4; ++mf)
#pragma unroll
    for (int r = 0; r < 4; ++r) {
      const int row = rb * 64 + mf * 16 + kg * 4 + r;
      const float gi = acc1[mf][0][r] + b4[0];
      const float gg = acc1[mf][1][r] + b4[1];
      const float gf = acc1[mf][2][r] + b4[2];
      const float go = acc1[mf][3][r] + b4[3];
      const float c0v = c0[(size_t)row * 256 + hcol];
      const float c1v = sigf(gf) * c0v + sigf(gi) * tanhf(gg);
      const float h1v = sigf(go) * tanhf(c1v);
      d_out[(size_t)row * 256 + hcol]  = h1v;
      out_c1[(size_t)row * 256 + hcol] = c1v;
    }
}

// ---------------------------------------------------------------------------
extern "C" void kernel_launch(void* const* d_in, const int* in_sizes, int n_in,
                              void* d_out, int out_size, void* d_ws, size_t ws_size,
                              hipStream_t stream)
{
  (void)in_sizes; (void)n_in; (void)out_size; (void)ws_size;
  const float* x       = (const float*)d_in[0];
  const float* h0      = (const float*)d_in[1];
  const float* c0      = (const float*)d_in[2];
  const float* hhat0   = (const float*)d_in[3];
  const float* chat0   = (const float*)d_in[4];
  const float* hweight = (const float*)d_in[5];
  const float* hbias   = (const float*)d_in[6];
  const float* zw_h    = (const float*)d_in[7];
  const float* zw_x    = (const float*)d_in[8];
  const float* zw_b    = (const float*)d_in[9];
  const float* zb_h    = (const float*)d_in[10];
  const float* zb_x    = (const float*)d_in[11];
  const float* dw_h    = (const float*)d_in[12];
  const float* dw_x    = (const float*)d_in[13];
  const float* dw_b    = (const float*)d_in[14];
  const float* weight  = (const float*)d_in[15];
  const float* bias    = (const float*)d_in[16];

  // workspace layout (bytes), all 16B-aligned; total ~25.7 MB
  char* wsb = (char*)d_ws;
  u16*   zbuf    = (u16*)(wsb + 0);            // B*192*2        = 25165824
  u16*   hw_ts   = (u16*)(wsb + 25165824);     // 2*8*16384*2    = 524288
  u16*   w_ts    = (u16*)(wsb + 25690112);     // 4*6*16384*2    = 786432
  u16*   dwh_ts  = (u16*)(wsb + 26476544);     // 4*16384*2      = 131072
  u16*   dwx_ts  = (u16*)(wsb + 26607616);
  u16*   dwb_ts  = (u16*)(wsb + 26738688);
  u16*   zw_ts   = (u16*)(wsb + 26869760);     // 2*12288*2      = 49152
  float* hbias_r = (float*)(wsb + 26918912);   // 512*4
  float* bias_r  = (float*)(wsb + 26920960);   // 1024*4
  float* zbias_r = (float*)(wsb + 26925056);   // 192*4

  hlstm_prep<<<dim3(512), dim3(256), 0, stream>>>(
      hweight, hbias, zw_h, zw_x, zw_b, zb_h, zb_x, dw_h, dw_x, dw_b, weight, bias,
      hw_ts, hbias_r, w_ts, bias_r, dwh_ts, dwx_ts, dwb_ts, zw_ts, zbias_r);

  hlstm_k1<<<dim3(1024, 2), dim3(256), 0, stream>>>(
      x, h0, hhat0, chat0, hw_ts, hbias_r, (float*)d_out);

  const float* hhat1 = (const float*)d_out + (size_t)BATCH * 512;
  hlstm_k15<<<dim3(1024), dim3(256), 0, stream>>>(hhat1, zw_ts, zbias_r, zbuf);

  hlstm_k2<<<dim3(1024, 4), dim3(256), 0, stream>>>(
      x, h0, c0, w_ts, bias_r, dwh_ts, dwx_ts, dwb_ts, zbuf, (float*)d_out);
}